// Round 9
// baseline (183.119 us; speedup 1.0000x reference)
//
#include <hip/hip_runtime.h>

typedef unsigned int uint;
typedef unsigned short ushort;

// N=50000 nodes, E=800000 edges, F_in=128, heads=4, C1=32 (concat->128), C2=64 (mean->64)
// R20: R19 + degree-bucketed node permutation (nodeord). bfinal counting-sorts each
// 256-node window by deg>>4 (8 buckets, ~free: it already holds per-node degree). agg1/agg2
// process nodes in permuted order so the 4 nodes of a wave have similar chunk counts --
// removes the ~27% padding iterations from wave max(deg) imbalance. Outputs still indexed
// by true node id (agg2 epilogue maps MFMA rows via 16-entry LDS table). Gather bytes and
// pattern unchanged (isolates iteration count vs byte-service as the agg limiter).

__device__ __forceinline__ float leaky(float x) { return x >= 0.f ? x : 0.2f * x; }
__device__ __forceinline__ float b2f(ushort h) { return __uint_as_float(((uint)h) << 16); }
__device__ __forceinline__ ushort f2b(float f) {
    uint u = __float_as_uint(f);
    return (ushort)((u + 0x7FFF + ((u >> 16) & 1)) >> 16);  // RNE
}

#if defined(__has_builtin)
#if __has_builtin(__builtin_amdgcn_fdot2_f32_bf16)
#define HAS_DOT2 1
#endif
#endif
#ifndef HAS_DOT2
#define HAS_DOT2 0
#endif

#if HAS_DOT2
typedef __bf16 bf16v2 __attribute__((ext_vector_type(2)));
__device__ __forceinline__ float dot2bf(uint h2, uint w2, float c) {
    return __builtin_amdgcn_fdot2_f32_bf16(__builtin_bit_cast(bf16v2, h2),
                                           __builtin_bit_cast(bf16v2, w2), c, false);
}
#define DOT2PAIR(hE, hE1, wpk, a0, a1)                                  \
    a0 = dot2bf(__builtin_amdgcn_perm(hE, hE1, 0x01000504), wpk, a0);   \
    a1 = dot2bf(__builtin_amdgcn_perm(hE, hE1, 0x03020706), wpk, a1);
#else
#define DOT2PAIR(hE, hE1, wpk, a0, a1)                                  \
    {                                                                   \
        float wlo = __uint_as_float((wpk) << 16);                       \
        float whi = __uint_as_float((wpk) & 0xffff0000u);               \
        a0 = fmaf(wlo, __uint_as_float((hE) << 16), a0);                \
        a1 = fmaf(wlo, __uint_as_float((hE) & 0xffff0000u), a1);        \
        a0 = fmaf(whi, __uint_as_float((hE1) << 16), a0);               \
        a1 = fmaf(whi, __uint_as_float((hE1) & 0xffff0000u), a1);       \
    }
#endif

// ---- block-local input-format detection (used where no cross-block ordering exists) ----
__device__ __forceinline__ int detect_bf_local(const void* xin) {
    __shared__ int s_sane;
    if (threadIdx.x == 0) s_sane = 0;
    __syncthreads();
    ushort v = ((const ushort*)xin)[2 * threadIdx.x];
    int ex = (v >> 7) & 0xFF;
    if (v == 0 || (ex >= 100 && ex <= 135)) atomicAdd(&s_sane, 1);
    __syncthreads();
    return s_sane >= 230;
}
__device__ __forceinline__ int detect_is64_local(const int* ei) {
    __shared__ int s_odd;
    if (threadIdx.x == 0) s_odd = 0;
    __syncthreads();
    if (threadIdx.x < 64 && ei[2 * threadIdx.x + 1] != 0) atomicOr(&s_odd, 1);
    __syncthreads();
    return s_odd == 0;
}

__device__ __forceinline__ float rdf(const void* p_, int i, int bf) {
    return bf ? b2f(((const ushort*)p_)[i]) : ((const float*)p_)[i];
}

__device__ __forceinline__ int edge_dst(const int* __restrict__ ei, int E, int e, int is64) {
    return (e >= E) ? (e - E) : (is64 ? ei[2 * E + 2 * e] : ei[E + e]);
}

// ---------------- prep (merged): W1T, smalls+flags, w2t8, W2sT, bhist ----------------
// grid = 64 + 1 + 4 + 128 + NBH blocks. bcnt pre-zeroed by hipMemsetAsync.
__global__ void prep_kernel(const void* __restrict__ x, const void* __restrict__ W1,
                            const void* __restrict__ as1, const void* __restrict__ ad1,
                            const void* __restrict__ b1, const void* __restrict__ b2,
                            const void* __restrict__ W2, const void* __restrict__ as2,
                            const void* __restrict__ ad2, const int* __restrict__ ei,
                            int E, int ET,
                            ushort* __restrict__ W1T, float* __restrict__ att1,
                            float* __restrict__ b1f, float* __restrict__ b2f_,
                            float* __restrict__ w2t8, ushort* __restrict__ W2sT,
                            int* __restrict__ flagI, int* __restrict__ flagF,
                            int* __restrict__ bcnt) {
    int b = blockIdx.x, t = threadIdx.x;
    if (b < 64) {  // W1 [128 k][128 n] -> W1T [n][k]
        int bf = detect_bf_local(x);
        int i = b * 256 + t;
        int k = i >> 7, n = i & 127;
        W1T[n * 128 + k] = bf ? ((const ushort*)W1)[i] : f2b(((const float*)W1)[i]);
        return;
    }
    b -= 64;
    if (b == 0) {  // smalls + global flags
        int bf = detect_bf_local(x);
        int is64 = detect_is64_local(ei);
        if (t == 0) { *flagF = bf; *flagI = is64; }
        for (int i = t; i < 512; i += 256) {
            if (i < 128)      att1[i] = rdf(as1, i, bf);
            else if (i < 256) att1[i] = rdf(ad1, i - 128, bf);
            else if (i < 384) b1f[i - 256] = rdf(b1, i - 256, bf);
            else if (i < 448) b2f_[i - 384] = rdf(b2, i - 384, bf);
        }
        return;
    }
    b -= 1;
    if (b < 4) {  // w2t8: 1024 = 8 o x 128 k
        int bf = detect_bf_local(x);
        int idx = b * 256 + t;
        int o = idx >> 7, k = idx & 127, h = o & 3;
        const void* att = (o < 4) ? as2 : ad2;
        float s = 0.f;
        for (int c = 0; c < 64; ++c) s += rdf(W2, k * 256 + h * 64 + c, bf) * rdf(att, h * 64 + c, bf);
        w2t8[o * 128 + k] = s;
        return;
    }
    b -= 4;
    if (b < 128) {  // W2sT: 32768 = 64 c x 512 hk
        int bf = detect_bf_local(x);
        int idx = b * 256 + t;
        int c = idx >> 9, hk = idx & 511;
        int h = hk >> 7, k = hk & 127;
        W2sT[c * 512 + hk] = f2b(0.25f * rdf(W2, k * 256 + h * 64 + c, bf));
        return;
    }
    b -= 128;
    {  // bhist role (bucketed CSR pass 1)
        int is64 = detect_is64_local(ei);
        __shared__ int bins[256];
        bins[t] = 0;
        __syncthreads();
        int base = b * 4096;
        for (int i = 0; i < 16; ++i) {
            int e = base + i * 256 + t;
            if (e < ET) atomicAdd(&bins[edge_dst(ei, E, e, is64) >> 8], 1);
        }
        __syncthreads();
        if (bins[t]) atomicAdd(&bcnt[t], bins[t]);
    }
}

// ---------------- gemm1 device body: h1 = x@W1 (bf16) + fused attdot1 ----------------
typedef __attribute__((ext_vector_type(8))) short bf16x8;
typedef __attribute__((ext_vector_type(4))) float floatx4;

__device__ __forceinline__ void gemm1_body(
    int blk, const void* __restrict__ xraw, const int* __restrict__ flagF,
    const ushort* __restrict__ BT, ushort* __restrict__ C,
    const float* __restrict__ att, float4* __restrict__ asrc4, float4* __restrict__ adst4,
    int M) {
    constexpr int K = 128, NT = 8;
    int lane = threadIdx.x & 63, wv = threadIdx.x >> 6;
    int row0 = (blk * 4 + wv) * 16;
    if (row0 >= M) return;
    int m = lane & 15, quad = lane >> 4;
    int rowa = min(row0 + m, M - 1);
    bf16x8 af[4];
    if (*flagF) {  // input already bf16
        const bf16x8* arow = (const bf16x8*)((const ushort*)xraw + (size_t)rowa * K);
#pragma unroll
        for (int kk = 0; kk < 4; ++kk) af[kk] = arow[4 * kk + quad];
    } else {       // f32 input: convert in-register (same f2b RNE as a prep pass would)
        const float4* arw = (const float4*)((const float*)xraw + (size_t)rowa * K);
#pragma unroll
        for (int kk = 0; kk < 4; ++kk) {
            float4 fa = arw[2 * (4 * kk + quad)];
            float4 fb = arw[2 * (4 * kk + quad) + 1];
            bf16x8 tv;
            tv[0] = (short)f2b(fa.x); tv[1] = (short)f2b(fa.y);
            tv[2] = (short)f2b(fa.z); tv[3] = (short)f2b(fa.w);
            tv[4] = (short)f2b(fb.x); tv[5] = (short)f2b(fb.y);
            tv[6] = (short)f2b(fb.z); tv[7] = (short)f2b(fb.w);
            af[kk] = tv;
        }
    }
    floatx4 acc[NT] = {};
#pragma unroll
    for (int nt = 0; nt < NT; ++nt) {
        const bf16x8* brow = (const bf16x8*)(BT + (size_t)(nt * 16 + m) * K);
#pragma unroll
        for (int kk = 0; kk < 4; ++kk)
            acc[nt] = __builtin_amdgcn_mfma_f32_16x16x32_bf16(af[kk], brow[4 * kk + quad], acc[nt], 0, 0, 0);
    }
    // C/D layout: col = lane&15, row = quad*4 + reg
#pragma unroll
    for (int nt = 0; nt < NT; ++nt)
#pragma unroll
        for (int r = 0; r < 4; ++r) {
            int row = row0 + quad * 4 + r;
            if (row < M) C[(size_t)row * 128 + nt * 16 + m] = f2b(acc[nt][r]);
        }
    float attS[NT], attD[NT];
#pragma unroll
    for (int nt = 0; nt < NT; ++nt) { attS[nt] = att[nt * 16 + m]; attD[nt] = att[128 + nt * 16 + m]; }
#pragma unroll
    for (int r = 0; r < 4; ++r) {
        float ps[4] = {0, 0, 0, 0}, pd[4] = {0, 0, 0, 0};
#pragma unroll
        for (int nt = 0; nt < NT; ++nt) {
            int h = nt / 2;  // layer-1 head = col/32
            ps[h] = fmaf(acc[nt][r], attS[nt], ps[h]);
            pd[h] = fmaf(acc[nt][r], attD[nt], pd[h]);
        }
#pragma unroll
        for (int off = 1; off < 16; off <<= 1) {
#pragma unroll
            for (int h = 0; h < 4; ++h) {
                ps[h] += __shfl_xor(ps[h], off, 64);
                pd[h] += __shfl_xor(pd[h], off, 64);
            }
        }
        int row = row0 + quad * 4 + r;
        if (m == 0 && row < M) {
            asrc4[row] = make_float4(ps[0], ps[1], ps[2], ps[3]);
            adst4[row] = make_float4(pd[0], pd[1], pd[2], pd[3]);
        }
    }
}

// ======== partg: fused CSR pass-2 (part role, blocks [0,npart)) + gemm1 role ========
__global__ __launch_bounds__(256) void partg_kernel(
    const int* __restrict__ ei, int E, int ET, const int* __restrict__ flagI,
    const int* __restrict__ bcnt, int* __restrict__ gofs, uint* __restrict__ ebuf,
    int NBUK, int npart,
    const void* __restrict__ xraw, const int* __restrict__ flagF,
    const ushort* __restrict__ BT, ushort* __restrict__ C, const float* __restrict__ att,
    float4* __restrict__ asrc4, float4* __restrict__ adst4, int M) {
    if ((int)blockIdx.x >= npart) {
        gemm1_body(blockIdx.x - npart, xraw, flagF, BT, C, att, asrc4, adst4, M);
        return;
    }
    __shared__ uint stage[8192];
    __shared__ int cnt_s[256], sc[256], sc2[256], lbase[257], cur[256], gb[256];
    int t = threadIdx.x;
    int base = blockIdx.x * 8192;
    cnt_s[t] = 0;
    __syncthreads();
    int is64 = *flagI;
    uint pk[32];
    short bk[32];
#pragma unroll
    for (int i = 0; i < 32; ++i) {
        int e = base + i * 256 + t;
        if (e < ET) {
            int src, dst;
            if (e >= E) { src = dst = e - E; }
            else if (is64) { src = ei[2 * e]; dst = ei[2 * E + 2 * e]; }
            else           { src = ei[e];     dst = ei[E + e]; }
            pk[i] = (uint)src | ((uint)dst << 16);
            bk[i] = (short)(dst >> 8);
            atomicAdd(&cnt_s[bk[i]], 1);
        } else bk[i] = -1;
    }
    __syncthreads();
    int v = cnt_s[t];
    int v2 = (t < NBUK) ? bcnt[t] : 0;   // global bucket counts (final after prep)
    sc[t] = v;
    sc2[t] = v2;
    __syncthreads();
    for (int off = 1; off < 256; off <<= 1) {
        int a  = (t >= off) ? sc[t - off]  : 0;
        int a2 = (t >= off) ? sc2[t - off] : 0;
        __syncthreads();
        sc[t] += a; sc2[t] += a2;
        __syncthreads();
    }
    lbase[t + 1] = sc[t];
    cur[t] = sc[t] - v;        // exclusive (local chunk)
    int bbx = sc2[t] - v2;     // exclusive (global buckets) == old bbase[t]
    if (t == 0) lbase[0] = 0;
    __syncthreads();
#pragma unroll
    for (int i = 0; i < 32; ++i)
        if (bk[i] >= 0) {
            int slot = atomicAdd(&cur[bk[i]], 1);
            stage[slot] = pk[i];
        }
    __syncthreads();
    if (t < NBUK) {
        int c = lbase[t + 1] - lbase[t];
        if (c > 0) gb[t] = bbx + atomicAdd(&gofs[t], c);
    }
    __syncthreads();
    int total = lbase[256];
    for (int i = t; i < total; i += 256) {
        int lo = 0, hi = 255;  // largest b with lbase[b] <= i
        while (lo < hi) { int mid = (lo + hi + 1) >> 1; if (lbase[mid] <= i) lo = mid; else hi = mid - 1; }
        ebuf[gb[lo] + (i - lbase[lo])] = stage[i];
    }
}

// fused per-bucket: local bcnt scan -> hist -> scan -> rowptr -> place -> nodeord
// sort key = (dst_local<<3) | (src>>13): rows contiguous per dst, src-segment-ordered.
// R20: tail = 8-bucket counting sort of the window's nodes by deg>>4 -> nodeord[].
__global__ __launch_bounds__(256) void bfinal_kernel(const uint* __restrict__ ebuf,
                                                     const int* __restrict__ bcnt,
                                                     int* __restrict__ rowptr,
                                                     int* __restrict__ ecol,
                                                     int* __restrict__ nodeord,
                                                     int N, int NBUK) {
    __shared__ int hist[2048], cur2[2048], ws[4], bb[256];
    __shared__ int kh[8], kbs[8];
    int b = blockIdx.x, t = threadIdx.x;
    int lane = t & 63, wid = t >> 6;
    int d0 = b << 8;
    // local inclusive scan of bcnt -> bucket bounds
    bb[t] = (t < NBUK) ? bcnt[t] : 0;
#pragma unroll
    for (int j = 0; j < 8; ++j) hist[t * 8 + j] = 0;
    if (t < 8) kh[t] = 0;
    __syncthreads();
    for (int off = 1; off < 256; off <<= 1) {
        int a = (t >= off) ? bb[t - off] : 0;
        __syncthreads();
        bb[t] += a;
        __syncthreads();
    }
    int s = (b == 0) ? 0 : bb[b - 1];
    int e2 = bb[b];
    int total = bb[255];
    for (int i = s + t; i < e2; i += 256) {
        uint pk = ebuf[i];
        int key = (((int)(pk >> 16) - d0) << 3) | (int)((pk & 0xffffu) >> 13);
        atomicAdd(&hist[key], 1);
    }
    __syncthreads();
    int loc[8];
    int v = 0;
#pragma unroll
    for (int j = 0; j < 8; ++j) { loc[j] = v; v += hist[t * 8 + j]; }  // v = deg(node d0+t)
    int incl = v;
#pragma unroll
    for (int off = 1; off < 64; off <<= 1) {
        int a = __shfl_up(incl, off, 64);
        if (lane >= off) incl += a;
    }
    if (lane == 63) ws[wid] = incl;
    __syncthreads();
    if (t == 0) {
        int acc = 0;
        for (int j = 0; j < 4; ++j) { int x = ws[j]; ws[j] = acc; acc += x; }
    }
    __syncthreads();
    int excl = incl - v + ws[wid];
    int d = d0 + t;
    bool dvalid = d < N;
    if (dvalid) rowptr[d] = s + excl;
#pragma unroll
    for (int j = 0; j < 8; ++j) cur2[t * 8 + j] = s + excl + loc[j];
    if (b == NBUK - 1 && t == 0) rowptr[N] = total;
    __syncthreads();
    for (int i = s + t; i < e2; i += 256) {
        uint pk = ebuf[i];
        int key = (((int)(pk >> 16) - d0) << 3) | (int)((pk & 0xffffu) >> 13);
        int pos = atomicAdd(&cur2[key], 1);
        ecol[pos] = (int)(pk & 0xffffu);
    }
    // ---- degree-bucketed node permutation for this 256-node window ----
    int dkey = dvalid ? min(v >> 4, 7) : 0;
    if (dvalid) atomicAdd(&kh[dkey], 1);
    __syncthreads();
    if (t == 0) {
        int acc = 0;
        for (int j = 0; j < 8; ++j) { int x = kh[j]; kbs[j] = acc; acc += x; kh[j] = 0; }
    }
    __syncthreads();
    if (dvalid) {
        int r = kbs[dkey] + atomicAdd(&kh[dkey], 1);
        nodeord[d0 + r] = d;
    }
}

// ---- fallback CSR (N > 65536) ----
__global__ void hist_kernel(const int* __restrict__ ei, int E, int N,
                            const int* __restrict__ flag, int* __restrict__ deg) {
    int e = blockIdx.x * blockDim.x + threadIdx.x;
    if (e >= E + N) return;
    atomicAdd(&deg[edge_dst(ei, E, e, *flag)], 1);
}
__global__ void scatter_kernel(const int* __restrict__ ei, int E, int N,
                               const int* __restrict__ flag, const int* __restrict__ rowptr,
                               int* __restrict__ cnt, int* __restrict__ ecol) {
    int e = blockIdx.x * blockDim.x + threadIdx.x;
    if (e >= E + N) return;
    int src, dst;
    if (e >= E) { src = dst = e - E; }
    else if (*flag) { src = ei[2 * e]; dst = ei[2 * E + 2 * e]; }
    else            { src = ei[e];     dst = ei[E + e]; }
    int pos = rowptr[dst] + atomicAdd(&cnt[dst], 1);
    ecol[pos] = src;
}
__global__ __launch_bounds__(1024) void scan1_kernel(const int* __restrict__ deg,
                                                     int* __restrict__ tmp,
                                                     int* __restrict__ bsum, int n) {
    __shared__ int ws[16];
    int tid = threadIdx.x, lane = tid & 63, wid = tid >> 6;
    int i = blockIdx.x * 1024 + tid;
    int v = (i < n) ? deg[i] : 0;
    int incl = v;
#pragma unroll
    for (int off = 1; off < 64; off <<= 1) {
        int t2 = __shfl_up(incl, off, 64);
        if (lane >= off) incl += t2;
    }
    if (lane == 63) ws[wid] = incl;
    __syncthreads();
    if (tid < 16) {
        int wv_ = ws[tid], winc = wv_;
#pragma unroll
        for (int off = 1; off < 16; off <<= 1) {
            int t2 = __shfl_up(winc, off, 16);
            if (tid >= off) winc += t2;
        }
        ws[tid] = winc - wv_;
    }
    __syncthreads();
    int excl = incl - v + ws[wid];
    if (i < n) tmp[i] = excl;
    if (tid == 1023) bsum[blockIdx.x] = excl + v;
}
__global__ void scan2_kernel(int* __restrict__ bsum, int nb) {
    int lane = threadIdx.x;
    int v = (lane < nb) ? bsum[lane] : 0;
    int incl = v;
    for (int off = 1; off < 64; off <<= 1) {
        int t = __shfl_up(incl, off, 64);
        if (lane >= off) incl += t;
    }
    int total = __shfl(incl, nb - 1, 64);
    if (lane < nb) bsum[lane] = incl - v;
    if (lane == 0) bsum[nb] = total;
}
__global__ void scan3_kernel(const int* __restrict__ tmp, const int* __restrict__ bsum,
                             int* __restrict__ rowptr, int* __restrict__ cnt,
                             int* __restrict__ nodeord, int n, int nb) {
    int i = blockIdx.x * blockDim.x + threadIdx.x;
    if (i > n) return;
    rowptr[i] = (i == n) ? bsum[nb] : tmp[i] + bsum[i >> 10];
    if (i < n) { cnt[i] = 0; nodeord[i] = i; }  // identity perm (fallback)
}

// standalone gemm1 (fallback path)
__global__ __launch_bounds__(256) void gemm1_kernel(
    const void* __restrict__ xraw, const int* __restrict__ flagF,
    const ushort* __restrict__ BT, ushort* __restrict__ C,
    const float* __restrict__ att, float4* __restrict__ asrc4, float4* __restrict__ adst4, int M) {
    gemm1_body(blockIdx.x, xraw, flagF, BT, C, att, asrc4, adst4, M);
}

// ---------------- agg1: 4 nodes/wave (16 lanes/node, 8 ch/lane); h1 -> hL1 + attdot2 ------
// R20: nodes taken in nodeord (degree-bucketed) order; outputs indexed by true node id.
__global__ __launch_bounds__(256) void agg1_kernel(
    const ushort* __restrict__ hsrc, const float4* __restrict__ a_src4,
    const float4* __restrict__ a_dst4, const int* __restrict__ rowptr,
    const int* __restrict__ ecol, const int* __restrict__ nodeord,
    const float* __restrict__ bias, const float* __restrict__ w2t8,
    uint4* __restrict__ outz, float4* __restrict__ asrc2, float4* __restrict__ adst2, int N) {
    constexpr int SH = 7;  // row = 128 ush
    __shared__ __align__(16) ushort elds[4][4][4][20];  // [wave][head][quarter][16+pad]
    int lane = threadIdx.x & 63, wv = threadIdx.x >> 6;
    int q = lane >> 4, c = lane & 15, qbase = q << 4;
    int gid = blockIdx.x * 16 + wv * 4 + q;
    bool nv = gid < N;
    int n = nv ? nodeord[gid] : 0;
    int start = 0, end = 0;
    if (nv) { start = rowptr[n]; end = rowptr[n + 1]; }
    int deg = end - start;
    float4 ad = nv ? a_dst4[n] : make_float4(0.f, 0.f, 0.f, 0.f);
    int hh = c >> 2;               // lane's channels 8c..8c+7 all in layer-1 head c/4
    uint laneoff = (uint)c * 8;    // ushort offset (8 ch/lane = 16B)
    float acc[8] = {};
    float ss0 = 0.f, ss1 = 0.f, ss2 = 0.f, ss3 = 0.f;

    for (int cs = 0; cs < deg; cs += 16) {
        int len = min(16, deg - cs);
        bool v = c < len;
        int sv = v ? ecol[start + cs + c] : 0;
        float4 as = a_src4[sv];
        float e0 = v ? __expf(fminf(leaky(as.x + ad.x), 60.f)) : 0.f;
        float e1 = v ? __expf(fminf(leaky(as.y + ad.y), 60.f)) : 0.f;
        float e2 = v ? __expf(fminf(leaky(as.z + ad.z), 60.f)) : 0.f;
        float e3 = v ? __expf(fminf(leaky(as.w + ad.w), 60.f)) : 0.f;
        ushort r0 = f2b(e0), r1 = f2b(e1), r2 = f2b(e2), r3 = f2b(e3);
        elds[wv][0][q][c] = r0; elds[wv][1][q][c] = r1;
        elds[wv][2][q][c] = r2; elds[wv][3][q][c] = r3;
        ss0 += b2f(r0); ss1 += b2f(r1); ss2 += b2f(r2); ss3 += b2f(r3);
        for (int e = 0; e < len; e += 4) {
            int s0 = __shfl(sv, qbase + e + 0, 64);
            int s1 = __shfl(sv, qbase + e + 1, 64);
            int s2 = __shfl(sv, qbase + e + 2, 64);
            int s3 = __shfl(sv, qbase + e + 3, 64);
            uint2 w = *(const uint2*)&elds[wv][hh][q][e];  // (a_e,a_e+1),(a_e+2,a_e+3)
            uint4 h0 = *(const uint4*)(hsrc + (((uint)s0) << SH) + laneoff);
            uint4 h1 = *(const uint4*)(hsrc + (((uint)s1) << SH) + laneoff);
            uint4 h2 = *(const uint4*)(hsrc + (((uint)s2) << SH) + laneoff);
            uint4 h3 = *(const uint4*)(hsrc + (((uint)s3) << SH) + laneoff);
            DOT2PAIR(h0.x, h1.x, w.x, acc[0], acc[1]); DOT2PAIR(h0.y, h1.y, w.x, acc[2], acc[3]);
            DOT2PAIR(h0.z, h1.z, w.x, acc[4], acc[5]); DOT2PAIR(h0.w, h1.w, w.x, acc[6], acc[7]);
            DOT2PAIR(h2.x, h3.x, w.y, acc[0], acc[1]); DOT2PAIR(h2.y, h3.y, w.y, acc[2], acc[3]);
            DOT2PAIR(h2.z, h3.z, w.y, acc[4], acc[5]); DOT2PAIR(h2.w, h3.w, w.y, acc[6], acc[7]);
        }
    }
#pragma unroll
    for (int off = 1; off < 16; off <<= 1) {  // within-quarter reduce
        ss0 += __shfl_xor(ss0, off, 64); ss1 += __shfl_xor(ss1, off, 64);
        ss2 += __shfl_xor(ss2, off, 64); ss3 += __shfl_xor(ss3, off, 64);
    }
    if (!nv) return;
    float ih = (hh == 0) ? 1.f / (ss0 + 1e-16f) : (hh == 1) ? 1.f / (ss1 + 1e-16f)
             : (hh == 2) ? 1.f / (ss2 + 1e-16f) : 1.f / (ss3 + 1e-16f);
    float4 bA = ((const float4*)bias)[2 * c], bB = ((const float4*)bias)[2 * c + 1];
    float o[8];
    o[0] = acc[0] * ih + bA.x; o[1] = acc[1] * ih + bA.y;
    o[2] = acc[2] * ih + bA.z; o[3] = acc[3] * ih + bA.w;
    o[4] = acc[4] * ih + bB.x; o[5] = acc[5] * ih + bB.y;
    o[6] = acc[6] * ih + bB.z; o[7] = acc[7] * ih + bB.w;
#pragma unroll
    for (int j = 0; j < 8; ++j) o[j] = o[j] > 0.f ? o[j] : __expf(o[j]) - 1.f;
    uint4 pk;
    pk.x = (uint)f2b(o[0]) | ((uint)f2b(o[1]) << 16);
    pk.y = (uint)f2b(o[2]) | ((uint)f2b(o[3]) << 16);
    pk.z = (uint)f2b(o[4]) | ((uint)f2b(o[5]) << 16);
    pk.w = (uint)f2b(o[6]) | ((uint)f2b(o[7]) << 16);
    outz[(size_t)n * 16 + c] = pk;

    // fused attdot2: a2[oidx] = hL1[n] . w2t8[oidx]
    float po[8];
#pragma unroll
    for (int oo = 0; oo < 8; ++oo) {
        float4 wA = ((const float4*)(w2t8 + oo * 128))[2 * c];
        float4 wB = ((const float4*)(w2t8 + oo * 128))[2 * c + 1];
        po[oo] = o[0] * wA.x + o[1] * wA.y + o[2] * wA.z + o[3] * wA.w
               + o[4] * wB.x + o[5] * wB.y + o[6] * wB.z + o[7] * wB.w;
    }
#pragma unroll
    for (int off = 1; off < 16; off <<= 1)
#pragma unroll
        for (int oo = 0; oo < 8; ++oo) po[oo] += __shfl_xor(po[oo], off, 64);
    if (c == 0) {
        asrc2[n] = make_float4(po[0], po[1], po[2], po[3]);
        adst2[n] = make_float4(po[4], po[5], po[6], po[7]);
    }
}

// ---- agg2: 4 nodes/wave per-head aggregate of hL1, FUSED output GEMM (K=512 vs W2sT) ----
// R20: permuted node order; epilogue maps MFMA rows to true node ids via nlds[16].
__global__ __launch_bounds__(256) void agg2_kernel(
    const ushort* __restrict__ hsrc, const float4* __restrict__ a_src4,
    const float4* __restrict__ a_dst4, const int* __restrict__ rowptr,
    const int* __restrict__ ecol, const int* __restrict__ nodeord,
    const ushort* __restrict__ W2sT, const float* __restrict__ b2,
    float* __restrict__ outp, int N) {
    constexpr int SH = 7;
    __shared__ __align__(16) ushort elds[4][4][4][20];  // [wave][head][quarter][16+pad]
    __shared__ __align__(16) ushort lds_a[16][520];     // 16 z2-rows (K=512), +8 pad
    __shared__ int nlds[16];
    int lane = threadIdx.x & 63, wv = threadIdx.x >> 6;
    int q = lane >> 4, c = lane & 15, qbase = q << 4;
    int gid = blockIdx.x * 16 + wv * 4 + q;
    bool nv = gid < N;
    int n = nv ? nodeord[gid] : 0;
    if (threadIdx.x < 16) {
        int g2 = blockIdx.x * 16 + threadIdx.x;
        nlds[threadIdx.x] = (g2 < N) ? nodeord[g2] : -1;
    }
    int start = 0, end = 0;
    if (nv) { start = rowptr[n]; end = rowptr[n + 1]; }
    int deg = end - start;
    float4 ad = nv ? a_dst4[n] : make_float4(0.f, 0.f, 0.f, 0.f);
    uint laneoff = (uint)c * 8;  // 8 ch/lane = 16B
    float a0_[8] = {}, a1_[8] = {}, a2_[8] = {}, a3_[8] = {};  // [head][8 ch]
    float ss0 = 0.f, ss1 = 0.f, ss2 = 0.f, ss3 = 0.f;

    for (int cs = 0; cs < deg; cs += 16) {
        int len = min(16, deg - cs);
        bool v = c < len;
        int sv = v ? ecol[start + cs + c] : 0;
        float4 as = a_src4[sv];
        float e0 = v ? __expf(fminf(leaky(as.x + ad.x), 60.f)) : 0.f;
        float e1 = v ? __expf(fminf(leaky(as.y + ad.y), 60.f)) : 0.f;
        float e2 = v ? __expf(fminf(leaky(as.z + ad.z), 60.f)) : 0.f;
        float e3 = v ? __expf(fminf(leaky(as.w + ad.w), 60.f)) : 0.f;
        ushort r0 = f2b(e0), r1 = f2b(e1), r2 = f2b(e2), r3 = f2b(e3);
        elds[wv][0][q][c] = r0; elds[wv][1][q][c] = r1;
        elds[wv][2][q][c] = r2; elds[wv][3][q][c] = r3;
        ss0 += b2f(r0); ss1 += b2f(r1); ss2 += b2f(r2); ss3 += b2f(r3);
        for (int e = 0; e < len; e += 4) {
            int s0 = __shfl(sv, qbase + e + 0, 64);
            int s1 = __shfl(sv, qbase + e + 1, 64);
            int s2 = __shfl(sv, qbase + e + 2, 64);
            int s3 = __shfl(sv, qbase + e + 3, 64);
            uint2 w0 = *(const uint2*)&elds[wv][0][q][e];
            uint2 w1 = *(const uint2*)&elds[wv][1][q][e];
            uint2 w2 = *(const uint2*)&elds[wv][2][q][e];
            uint2 w3 = *(const uint2*)&elds[wv][3][q][e];
            uint4 h0 = *(const uint4*)(hsrc + (((uint)s0) << SH) + laneoff);
            uint4 h1 = *(const uint4*)(hsrc + (((uint)s1) << SH) + laneoff);
            uint4 h2 = *(const uint4*)(hsrc + (((uint)s2) << SH) + laneoff);
            uint4 h3 = *(const uint4*)(hsrc + (((uint)s3) << SH) + laneoff);
            // row perms are shared (CSE) across the 4 head-weight lines
            DOT2PAIR(h0.x, h1.x, w0.x, a0_[0], a0_[1]); DOT2PAIR(h0.y, h1.y, w0.x, a0_[2], a0_[3]);
            DOT2PAIR(h0.z, h1.z, w0.x, a0_[4], a0_[5]); DOT2PAIR(h0.w, h1.w, w0.x, a0_[6], a0_[7]);
            DOT2PAIR(h0.x, h1.x, w1.x, a1_[0], a1_[1]); DOT2PAIR(h0.y, h1.y, w1.x, a1_[2], a1_[3]);
            DOT2PAIR(h0.z, h1.z, w1.x, a1_[4], a1_[5]); DOT2PAIR(h0.w, h1.w, w1.x, a1_[6], a1_[7]);
            DOT2PAIR(h0.x, h1.x, w2.x, a2_[0], a2_[1]); DOT2PAIR(h0.y, h1.y, w2.x, a2_[2], a2_[3]);
            DOT2PAIR(h0.z, h1.z, w2.x, a2_[4], a2_[5]); DOT2PAIR(h0.w, h1.w, w2.x, a2_[6], a2_[7]);
            DOT2PAIR(h0.x, h1.x, w3.x, a3_[0], a3_[1]); DOT2PAIR(h0.y, h1.y, w3.x, a3_[2], a3_[3]);
            DOT2PAIR(h0.z, h1.z, w3.x, a3_[4], a3_[5]); DOT2PAIR(h0.w, h1.w, w3.x, a3_[6], a3_[7]);
            DOT2PAIR(h2.x, h3.x, w0.y, a0_[0], a0_[1]); DOT2PAIR(h2.y, h3.y, w0.y, a0_[2], a0_[3]);
            DOT2PAIR(h2.z, h3.z, w0.y, a0_[4], a0_[5]); DOT2PAIR(h2.w, h3.w, w0.y, a0_[6], a0_[7]);
            DOT2PAIR(h2.x, h3.x, w1.y, a1_[0], a1_[1]); DOT2PAIR(h2.y, h3.y, w1.y, a1_[2], a1_[3]);
            DOT2PAIR(h2.z, h3.z, w1.y, a1_[4], a1_[5]); DOT2PAIR(h2.w, h3.w, w1.y, a1_[6], a1_[7]);
            DOT2PAIR(h2.x, h3.x, w2.y, a2_[0], a2_[1]); DOT2PAIR(h2.y, h3.y, w2.y, a2_[2], a2_[3]);
            DOT2PAIR(h2.z, h3.z, w2.y, a2_[4], a2_[5]); DOT2PAIR(h2.w, h3.w, w2.y, a2_[6], a2_[7]);
            DOT2PAIR(h2.x, h3.x, w3.y, a3_[0], a3_[1]); DOT2PAIR(h2.y, h3.y, w3.y, a3_[2], a3_[3]);
            DOT2PAIR(h2.z, h3.z, w3.y, a3_[4], a3_[5]); DOT2PAIR(h2.w, h3.w, w3.y, a3_[6], a3_[7]);
        }
    }
#pragma unroll
    for (int off = 1; off < 16; off <<= 1) {
        ss0 += __shfl_xor(ss0, off, 64); ss1 += __shfl_xor(ss1, off, 64);
        ss2 += __shfl_xor(ss2, off, 64); ss3 += __shfl_xor(ss3, off, 64);
    }
    // normalize (invalid nodes: acc=0 -> z=0) and stage z2 rows into LDS A-tile
    float i0 = 1.f / (ss0 + 1e-16f), i1 = 1.f / (ss1 + 1e-16f);
    float i2 = 1.f / (ss2 + 1e-16f), i3 = 1.f / (ss3 + 1e-16f);
    int slot = wv * 4 + q;
    uint4 pk;
    pk.x = (uint)f2b(a0_[0] * i0) | ((uint)f2b(a0_[1] * i0) << 16);
    pk.y = (uint)f2b(a0_[2] * i0) | ((uint)f2b(a0_[3] * i0) << 16);
    pk.z = (uint)f2b(a0_[4] * i0) | ((uint)f2b(a0_[5] * i0) << 16);
    pk.w = (uint)f2b(a0_[6] * i0) | ((uint)f2b(a0_[7] * i0) << 16);
    *(uint4*)&lds_a[slot][0 * 128 + 8 * c] = pk;
    pk.x = (uint)f2b(a1_[0] * i1) | ((uint)f2b(a1_[1] * i1) << 16);
    pk.y = (uint)f2b(a1_[2] * i1) | ((uint)f2b(a1_[3] * i1) << 16);
    pk.z = (uint)f2b(a1_[4] * i1) | ((uint)f2b(a1_[5] * i1) << 16);
    pk.w = (uint)f2b(a1_[6] * i1) | ((uint)f2b(a1_[7] * i1) << 16);
    *(uint4*)&lds_a[slot][1 * 128 + 8 * c] = pk;
    pk.x = (uint)f2b(a2_[0] * i2) | ((uint)f2b(a2_[1] * i2) << 16);
    pk.y = (uint)f2b(a2_[2] * i2) | ((uint)f2b(a2_[3] * i2) << 16);
    pk.z = (uint)f2b(a2_[4] * i2) | ((uint)f2b(a2_[5] * i2) << 16);
    pk.w = (uint)f2b(a2_[6] * i2) | ((uint)f2b(a2_[7] * i2) << 16);
    *(uint4*)&lds_a[slot][2 * 128 + 8 * c] = pk;
    pk.x = (uint)f2b(a3_[0] * i3) | ((uint)f2b(a3_[1] * i3) << 16);
    pk.y = (uint)f2b(a3_[2] * i3) | ((uint)f2b(a3_[3] * i3) << 16);
    pk.z = (uint)f2b(a3_[4] * i3) | ((uint)f2b(a3_[5] * i3) << 16);
    pk.w = (uint)f2b(a3_[6] * i3) | ((uint)f2b(a3_[7] * i3) << 16);
    *(uint4*)&lds_a[slot][3 * 128 + 8 * c] = pk;
    __syncthreads();

    // fused gemm2: wave wv computes out cols wv*16..+15 for the block's 16 nodes (K=512 MFMA)
    int m = lane & 15, quad = lane >> 4;
    const bf16x8* arow = (const bf16x8*)&lds_a[m][0];
    const bf16x8* brow = (const bf16x8*)(W2sT + (size_t)(wv * 16 + m) * 512);
    floatx4 acc2 = {};
#pragma unroll
    for (int kk = 0; kk < 16; ++kk)
        acc2 = __builtin_amdgcn_mfma_f32_16x16x32_bf16(arow[4 * kk + quad], brow[4 * kk + quad], acc2, 0, 0, 0);
    float bb = b2[wv * 16 + m];
#pragma unroll
    for (int r = 0; r < 4; ++r) {
        int row = quad * 4 + r;  // C/D: col=lane&15, row=quad*4+r
        int nd = nlds[row];
        if (nd >= 0) outp[(size_t)nd * 64 + wv * 16 + m] = acc2[r] + bb;
    }
}

// ---------------- launch ----------------
extern "C" void kernel_launch(void* const* d_in, const int* in_sizes, int n_in,
                              void* d_out, int out_size, void* d_ws, size_t ws_size,
                              hipStream_t stream) {
    // setup_inputs order: x, edge_index, W1, att_src1, att_dst1, bias1, W2, att_src2, att_dst2, bias2
    const void* x_raw = d_in[0];
    const int*  ei    = (const int*)d_in[1];
    const void* W1_p  = d_in[2];
    const void* as1_p = d_in[3];
    const void* ad1_p = d_in[4];
    const void* b1_p  = d_in[5];
    const void* W2_p  = d_in[6];
    const void* as2_p = d_in[7];
    const void* ad2_p = d_in[8];
    const void* b2_p  = d_in[9];

    const int F_IN = 128;
    const int N = in_sizes[0] / F_IN;   // 50000
    const int E = in_sizes[1] / 2;      // 800000
    const int ET = E + N;
    const int NB = (N + 1023) / 1024;
    const int NBUK = (N + 255) >> 8;    // buckets; packed path needs N<=65536
    const int NBH = (ET + 4095) / 4096; // bhist-role blocks inside prep

    char* p = (char*)d_ws;
    auto alloc = [&](size_t bytes) { char* r = p; p += (bytes + 255) & ~(size_t)255; return r; };
    ushort* W1T   = (ushort*)alloc(128 * 128 * 2);
    ushort* W2sT  = (ushort*)alloc(64 * 512 * 2);
    float*  att1f = (float*)alloc(256 * 4);
    float*  w2t8  = (float*)alloc(8 * 128 * 4);
    float*  b1f   = (float*)alloc(128 * 4);
    float*  b2f   = (float*)alloc(64 * 4);
    ushort* h1    = (ushort*)alloc((size_t)N * 128 * 2);
    ushort* hL1   = (ushort*)alloc((size_t)N * 128 * 2);
    float*  asrc1 = (float*)alloc((size_t)N * 4 * 4);
    float*  adst1 = (float*)alloc((size_t)N * 4 * 4);
    float*  asrc2 = (float*)alloc((size_t)N * 4 * 4);
    float*  adst2 = (float*)alloc((size_t)N * 4 * 4);
    int* nodeord = (int*)alloc((size_t)N * 4);
    int* deg    = (int*)alloc((size_t)N * 4);   // fallback only
    int* cnt    = (int*)alloc((size_t)N * 4);   // fallback only
    int* tmp    = (int*)alloc((size_t)N * 4);   // fallback only
    int* bsum   = (int*)alloc(128 * 4);         // fallback only
    int* rowptr = (int*)alloc((size_t)(N + 1) * 4);
    int* ecol   = (int*)alloc((size_t)ET * 4);
    uint* ebuf  = (uint*)alloc((size_t)ET * 4);
    int* bcnt   = (int*)alloc(256 * 4);
    int* gofs   = (int*)alloc(256 * 4);   // contiguous with bcnt (both 1024B, 256B-aligned)
    int* flagI  = (int*)alloc(256);
    int* flagF  = (int*)alloc(256);

    hipMemsetAsync(bcnt, 0, 2 * 256 * 4, stream);  // bcnt + gofs
    // merged prep: W1T + smalls/flags + w2t8 + W2sT + bhist (x-conv lives in gemm1 body)
    prep_kernel<<<64 + 1 + 4 + 128 + NBH, 256, 0, stream>>>(
        x_raw, W1_p, as1_p, ad1_p, b1_p, b2_p, W2_p, as2_p, ad2_p, ei, E, ET,
        W1T, att1f, b1f, b2f, w2t8, W2sT, flagI, flagF, bcnt);

    int gblocks = (N + 63) / 64;
    if (N <= 65536) {  // bucketed CSR; part fused with gemm1 (independent workloads)
        int npart = (ET + 8191) / 8192;
        partg_kernel<<<npart + gblocks, 256, 0, stream>>>(
            ei, E, ET, flagI, bcnt, gofs, ebuf, NBUK, npart,
            x_raw, flagF, W1T, h1, att1f, (float4*)asrc1, (float4*)adst1, N);
        bfinal_kernel<<<NBUK, 256, 0, stream>>>(ebuf, bcnt, rowptr, ecol, nodeord, N, NBUK);
    } else {  // fallback: random-scatter path
        hipMemsetAsync(deg, 0, (size_t)N * 4, stream);
        int eblocks = (ET + 255) / 256;
        hist_kernel<<<eblocks, 256, 0, stream>>>(ei, E, N, flagI, deg);
        scan1_kernel<<<NB, 1024, 0, stream>>>(deg, tmp, bsum, N);
        scan2_kernel<<<1, 64, 0, stream>>>(bsum, NB);
        scan3_kernel<<<(N + 256) / 256, 256, 0, stream>>>(tmp, bsum, rowptr, cnt, nodeord, N, NB);
        scatter_kernel<<<eblocks, 256, 0, stream>>>(ei, E, N, flagI, rowptr, cnt, ecol);
        gemm1_kernel<<<gblocks, 256, 0, stream>>>(
            x_raw, flagF, W1T, h1, att1f, (float4*)asrc1, (float4*)adst1, N);
    }

    int nblocks16 = (N + 15) / 16;
    // ---- layer 1 aggregation ----
    agg1_kernel<<<nblocks16, 256, 0, stream>>>(
        h1, (const float4*)asrc1, (const float4*)adst1, rowptr, ecol, nodeord, b1f, w2t8,
        (uint4*)hL1, (float4*)asrc2, (float4*)adst2, N);
    // ---- layer 2 (agg + output GEMM fused) ----
    agg2_kernel<<<nblocks16, 256, 0, stream>>>(
        hL1, (const float4*)asrc2, (const float4*)adst2, rowptr, ecol, nodeord, W2sT, b2f,
        (float*)d_out, N);
}

// Round 10
// 179.309 us; speedup vs baseline: 1.0213x; 1.0213x over previous
//
#include <hip/hip_runtime.h>

typedef unsigned int uint;
typedef unsigned short ushort;

// N=50000 nodes, E=800000 edges, F_in=128, heads=4, C1=32 (concat->128), C2=64 (mean->64)
// R21 = R19 verbatim (best measured: 179.5us). R20's degree-balanced permutation was the
// pre-registered discriminator and returned null -> aggs are byte-service-bound on the
// scattered 256B-row gather (~3.2 TB/s delivered ceiling; confirmed via R14/R17/R20 nulls,
// R15/R16 byte/width wins). Dispatches: memset, prep, partg(part+gemm1), bfinal, agg1, agg2.

__device__ __forceinline__ float leaky(float x) { return x >= 0.f ? x : 0.2f * x; }
__device__ __forceinline__ float b2f(ushort h) { return __uint_as_float(((uint)h) << 16); }
__device__ __forceinline__ ushort f2b(float f) {
    uint u = __float_as_uint(f);
    return (ushort)((u + 0x7FFF + ((u >> 16) & 1)) >> 16);  // RNE
}

#if defined(__has_builtin)
#if __has_builtin(__builtin_amdgcn_fdot2_f32_bf16)
#define HAS_DOT2 1
#endif
#endif
#ifndef HAS_DOT2
#define HAS_DOT2 0
#endif

#if HAS_DOT2
typedef __bf16 bf16v2 __attribute__((ext_vector_type(2)));
__device__ __forceinline__ float dot2bf(uint h2, uint w2, float c) {
    return __builtin_amdgcn_fdot2_f32_bf16(__builtin_bit_cast(bf16v2, h2),
                                           __builtin_bit_cast(bf16v2, w2), c, false);
}
#define DOT2PAIR(hE, hE1, wpk, a0, a1)                                  \
    a0 = dot2bf(__builtin_amdgcn_perm(hE, hE1, 0x01000504), wpk, a0);   \
    a1 = dot2bf(__builtin_amdgcn_perm(hE, hE1, 0x03020706), wpk, a1);
#else
#define DOT2PAIR(hE, hE1, wpk, a0, a1)                                  \
    {                                                                   \
        float wlo = __uint_as_float((wpk) << 16);                       \
        float whi = __uint_as_float((wpk) & 0xffff0000u);               \
        a0 = fmaf(wlo, __uint_as_float((hE) << 16), a0);                \
        a1 = fmaf(wlo, __uint_as_float((hE) & 0xffff0000u), a1);        \
        a0 = fmaf(whi, __uint_as_float((hE1) << 16), a0);               \
        a1 = fmaf(whi, __uint_as_float((hE1) & 0xffff0000u), a1);       \
    }
#endif

// ---- block-local input-format detection (used where no cross-block ordering exists) ----
__device__ __forceinline__ int detect_bf_local(const void* xin) {
    __shared__ int s_sane;
    if (threadIdx.x == 0) s_sane = 0;
    __syncthreads();
    ushort v = ((const ushort*)xin)[2 * threadIdx.x];
    int ex = (v >> 7) & 0xFF;
    if (v == 0 || (ex >= 100 && ex <= 135)) atomicAdd(&s_sane, 1);
    __syncthreads();
    return s_sane >= 230;
}
__device__ __forceinline__ int detect_is64_local(const int* ei) {
    __shared__ int s_odd;
    if (threadIdx.x == 0) s_odd = 0;
    __syncthreads();
    if (threadIdx.x < 64 && ei[2 * threadIdx.x + 1] != 0) atomicOr(&s_odd, 1);
    __syncthreads();
    return s_odd == 0;
}

__device__ __forceinline__ float rdf(const void* p_, int i, int bf) {
    return bf ? b2f(((const ushort*)p_)[i]) : ((const float*)p_)[i];
}

__device__ __forceinline__ int edge_dst(const int* __restrict__ ei, int E, int e, int is64) {
    return (e >= E) ? (e - E) : (is64 ? ei[2 * E + 2 * e] : ei[E + e]);
}

// ---------------- prep (merged): W1T, smalls+flags, w2t8, W2sT, bhist ----------------
// grid = 64 + 1 + 4 + 128 + NBH blocks. bcnt pre-zeroed by hipMemsetAsync.
__global__ void prep_kernel(const void* __restrict__ x, const void* __restrict__ W1,
                            const void* __restrict__ as1, const void* __restrict__ ad1,
                            const void* __restrict__ b1, const void* __restrict__ b2,
                            const void* __restrict__ W2, const void* __restrict__ as2,
                            const void* __restrict__ ad2, const int* __restrict__ ei,
                            int E, int ET,
                            ushort* __restrict__ W1T, float* __restrict__ att1,
                            float* __restrict__ b1f, float* __restrict__ b2f_,
                            float* __restrict__ w2t8, ushort* __restrict__ W2sT,
                            int* __restrict__ flagI, int* __restrict__ flagF,
                            int* __restrict__ bcnt) {
    int b = blockIdx.x, t = threadIdx.x;
    if (b < 64) {  // W1 [128 k][128 n] -> W1T [n][k]
        int bf = detect_bf_local(x);
        int i = b * 256 + t;
        int k = i >> 7, n = i & 127;
        W1T[n * 128 + k] = bf ? ((const ushort*)W1)[i] : f2b(((const float*)W1)[i]);
        return;
    }
    b -= 64;
    if (b == 0) {  // smalls + global flags
        int bf = detect_bf_local(x);
        int is64 = detect_is64_local(ei);
        if (t == 0) { *flagF = bf; *flagI = is64; }
        for (int i = t; i < 512; i += 256) {
            if (i < 128)      att1[i] = rdf(as1, i, bf);
            else if (i < 256) att1[i] = rdf(ad1, i - 128, bf);
            else if (i < 384) b1f[i - 256] = rdf(b1, i - 256, bf);
            else if (i < 448) b2f_[i - 384] = rdf(b2, i - 384, bf);
        }
        return;
    }
    b -= 1;
    if (b < 4) {  // w2t8: 1024 = 8 o x 128 k
        int bf = detect_bf_local(x);
        int idx = b * 256 + t;
        int o = idx >> 7, k = idx & 127, h = o & 3;
        const void* att = (o < 4) ? as2 : ad2;
        float s = 0.f;
        for (int c = 0; c < 64; ++c) s += rdf(W2, k * 256 + h * 64 + c, bf) * rdf(att, h * 64 + c, bf);
        w2t8[o * 128 + k] = s;
        return;
    }
    b -= 4;
    if (b < 128) {  // W2sT: 32768 = 64 c x 512 hk
        int bf = detect_bf_local(x);
        int idx = b * 256 + t;
        int c = idx >> 9, hk = idx & 511;
        int h = hk >> 7, k = hk & 127;
        W2sT[c * 512 + hk] = f2b(0.25f * rdf(W2, k * 256 + h * 64 + c, bf));
        return;
    }
    b -= 128;
    {  // bhist role (bucketed CSR pass 1)
        int is64 = detect_is64_local(ei);
        __shared__ int bins[256];
        bins[t] = 0;
        __syncthreads();
        int base = b * 4096;
        for (int i = 0; i < 16; ++i) {
            int e = base + i * 256 + t;
            if (e < ET) atomicAdd(&bins[edge_dst(ei, E, e, is64) >> 8], 1);
        }
        __syncthreads();
        if (bins[t]) atomicAdd(&bcnt[t], bins[t]);
    }
}

// ---------------- gemm1 device body: h1 = x@W1 (bf16) + fused attdot1 ----------------
typedef __attribute__((ext_vector_type(8))) short bf16x8;
typedef __attribute__((ext_vector_type(4))) float floatx4;

__device__ __forceinline__ void gemm1_body(
    int blk, const void* __restrict__ xraw, const int* __restrict__ flagF,
    const ushort* __restrict__ BT, ushort* __restrict__ C,
    const float* __restrict__ att, float4* __restrict__ asrc4, float4* __restrict__ adst4,
    int M) {
    constexpr int K = 128, NT = 8;
    int lane = threadIdx.x & 63, wv = threadIdx.x >> 6;
    int row0 = (blk * 4 + wv) * 16;
    if (row0 >= M) return;
    int m = lane & 15, quad = lane >> 4;
    int rowa = min(row0 + m, M - 1);
    bf16x8 af[4];
    if (*flagF) {  // input already bf16
        const bf16x8* arow = (const bf16x8*)((const ushort*)xraw + (size_t)rowa * K);
#pragma unroll
        for (int kk = 0; kk < 4; ++kk) af[kk] = arow[4 * kk + quad];
    } else {       // f32 input: convert in-register (same f2b RNE as a prep pass would)
        const float4* arw = (const float4*)((const float*)xraw + (size_t)rowa * K);
#pragma unroll
        for (int kk = 0; kk < 4; ++kk) {
            float4 fa = arw[2 * (4 * kk + quad)];
            float4 fb = arw[2 * (4 * kk + quad) + 1];
            bf16x8 tv;
            tv[0] = (short)f2b(fa.x); tv[1] = (short)f2b(fa.y);
            tv[2] = (short)f2b(fa.z); tv[3] = (short)f2b(fa.w);
            tv[4] = (short)f2b(fb.x); tv[5] = (short)f2b(fb.y);
            tv[6] = (short)f2b(fb.z); tv[7] = (short)f2b(fb.w);
            af[kk] = tv;
        }
    }
    floatx4 acc[NT] = {};
#pragma unroll
    for (int nt = 0; nt < NT; ++nt) {
        const bf16x8* brow = (const bf16x8*)(BT + (size_t)(nt * 16 + m) * K);
#pragma unroll
        for (int kk = 0; kk < 4; ++kk)
            acc[nt] = __builtin_amdgcn_mfma_f32_16x16x32_bf16(af[kk], brow[4 * kk + quad], acc[nt], 0, 0, 0);
    }
    // C/D layout: col = lane&15, row = quad*4 + reg
#pragma unroll
    for (int nt = 0; nt < NT; ++nt)
#pragma unroll
        for (int r = 0; r < 4; ++r) {
            int row = row0 + quad * 4 + r;
            if (row < M) C[(size_t)row * 128 + nt * 16 + m] = f2b(acc[nt][r]);
        }
    float attS[NT], attD[NT];
#pragma unroll
    for (int nt = 0; nt < NT; ++nt) { attS[nt] = att[nt * 16 + m]; attD[nt] = att[128 + nt * 16 + m]; }
#pragma unroll
    for (int r = 0; r < 4; ++r) {
        float ps[4] = {0, 0, 0, 0}, pd[4] = {0, 0, 0, 0};
#pragma unroll
        for (int nt = 0; nt < NT; ++nt) {
            int h = nt / 2;  // layer-1 head = col/32
            ps[h] = fmaf(acc[nt][r], attS[nt], ps[h]);
            pd[h] = fmaf(acc[nt][r], attD[nt], pd[h]);
        }
#pragma unroll
        for (int off = 1; off < 16; off <<= 1) {
#pragma unroll
            for (int h = 0; h < 4; ++h) {
                ps[h] += __shfl_xor(ps[h], off, 64);
                pd[h] += __shfl_xor(pd[h], off, 64);
            }
        }
        int row = row0 + quad * 4 + r;
        if (m == 0 && row < M) {
            asrc4[row] = make_float4(ps[0], ps[1], ps[2], ps[3]);
            adst4[row] = make_float4(pd[0], pd[1], pd[2], pd[3]);
        }
    }
}

// ======== partg: fused CSR pass-2 (part role, blocks [0,npart)) + gemm1 role ========
__global__ __launch_bounds__(256) void partg_kernel(
    const int* __restrict__ ei, int E, int ET, const int* __restrict__ flagI,
    const int* __restrict__ bcnt, int* __restrict__ gofs, uint* __restrict__ ebuf,
    int NBUK, int npart,
    const void* __restrict__ xraw, const int* __restrict__ flagF,
    const ushort* __restrict__ BT, ushort* __restrict__ C, const float* __restrict__ att,
    float4* __restrict__ asrc4, float4* __restrict__ adst4, int M) {
    if ((int)blockIdx.x >= npart) {
        gemm1_body(blockIdx.x - npart, xraw, flagF, BT, C, att, asrc4, adst4, M);
        return;
    }
    __shared__ uint stage[8192];
    __shared__ int cnt_s[256], sc[256], sc2[256], lbase[257], cur[256], gb[256];
    int t = threadIdx.x;
    int base = blockIdx.x * 8192;
    cnt_s[t] = 0;
    __syncthreads();
    int is64 = *flagI;
    uint pk[32];
    short bk[32];
#pragma unroll
    for (int i = 0; i < 32; ++i) {
        int e = base + i * 256 + t;
        if (e < ET) {
            int src, dst;
            if (e >= E) { src = dst = e - E; }
            else if (is64) { src = ei[2 * e]; dst = ei[2 * E + 2 * e]; }
            else           { src = ei[e];     dst = ei[E + e]; }
            pk[i] = (uint)src | ((uint)dst << 16);
            bk[i] = (short)(dst >> 8);
            atomicAdd(&cnt_s[bk[i]], 1);
        } else bk[i] = -1;
    }
    __syncthreads();
    int v = cnt_s[t];
    int v2 = (t < NBUK) ? bcnt[t] : 0;   // global bucket counts (final after prep)
    sc[t] = v;
    sc2[t] = v2;
    __syncthreads();
    for (int off = 1; off < 256; off <<= 1) {
        int a  = (t >= off) ? sc[t - off]  : 0;
        int a2 = (t >= off) ? sc2[t - off] : 0;
        __syncthreads();
        sc[t] += a; sc2[t] += a2;
        __syncthreads();
    }
    lbase[t + 1] = sc[t];
    cur[t] = sc[t] - v;        // exclusive (local chunk)
    int bbx = sc2[t] - v2;     // exclusive (global buckets) == old bbase[t]
    if (t == 0) lbase[0] = 0;
    __syncthreads();
#pragma unroll
    for (int i = 0; i < 32; ++i)
        if (bk[i] >= 0) {
            int slot = atomicAdd(&cur[bk[i]], 1);
            stage[slot] = pk[i];
        }
    __syncthreads();
    if (t < NBUK) {
        int c = lbase[t + 1] - lbase[t];
        if (c > 0) gb[t] = bbx + atomicAdd(&gofs[t], c);
    }
    __syncthreads();
    int total = lbase[256];
    for (int i = t; i < total; i += 256) {
        int lo = 0, hi = 255;  // largest b with lbase[b] <= i
        while (lo < hi) { int mid = (lo + hi + 1) >> 1; if (lbase[mid] <= i) lo = mid; else hi = mid - 1; }
        ebuf[gb[lo] + (i - lbase[lo])] = stage[i];
    }
}

// fused per-bucket: local bcnt scan -> hist -> scan -> rowptr -> place (one block/bucket)
// sort key = (dst_local<<3) | (src>>13): rows contiguous per dst, src-segment-ordered.
__global__ __launch_bounds__(256) void bfinal_kernel(const uint* __restrict__ ebuf,
                                                     const int* __restrict__ bcnt,
                                                     int* __restrict__ rowptr,
                                                     int* __restrict__ ecol, int N, int NBUK) {
    __shared__ int hist[2048], cur2[2048], ws[4], bb[256];
    int b = blockIdx.x, t = threadIdx.x;
    int lane = t & 63, wid = t >> 6;
    int d0 = b << 8;
    // local inclusive scan of bcnt -> bucket bounds
    bb[t] = (t < NBUK) ? bcnt[t] : 0;
#pragma unroll
    for (int j = 0; j < 8; ++j) hist[t * 8 + j] = 0;
    __syncthreads();
    for (int off = 1; off < 256; off <<= 1) {
        int a = (t >= off) ? bb[t - off] : 0;
        __syncthreads();
        bb[t] += a;
        __syncthreads();
    }
    int s = (b == 0) ? 0 : bb[b - 1];
    int e2 = bb[b];
    int total = bb[255];
    for (int i = s + t; i < e2; i += 256) {
        uint pk = ebuf[i];
        int key = (((int)(pk >> 16) - d0) << 3) | (int)((pk & 0xffffu) >> 13);
        atomicAdd(&hist[key], 1);
    }
    __syncthreads();
    int loc[8];
    int v = 0;
#pragma unroll
    for (int j = 0; j < 8; ++j) { loc[j] = v; v += hist[t * 8 + j]; }
    int incl = v;
#pragma unroll
    for (int off = 1; off < 64; off <<= 1) {
        int a = __shfl_up(incl, off, 64);
        if (lane >= off) incl += a;
    }
    if (lane == 63) ws[wid] = incl;
    __syncthreads();
    if (t == 0) {
        int acc = 0;
        for (int j = 0; j < 4; ++j) { int x = ws[j]; ws[j] = acc; acc += x; }
    }
    __syncthreads();
    int excl = incl - v + ws[wid];
    int d = d0 + t;
    if (d < N) rowptr[d] = s + excl;
#pragma unroll
    for (int j = 0; j < 8; ++j) cur2[t * 8 + j] = s + excl + loc[j];
    if (b == NBUK - 1 && t == 0) rowptr[N] = total;
    __syncthreads();
    for (int i = s + t; i < e2; i += 256) {
        uint pk = ebuf[i];
        int key = (((int)(pk >> 16) - d0) << 3) | (int)((pk & 0xffffu) >> 13);
        int pos = atomicAdd(&cur2[key], 1);
        ecol[pos] = (int)(pk & 0xffffu);
    }
}

// ---- fallback CSR (N > 65536) ----
__global__ void hist_kernel(const int* __restrict__ ei, int E, int N,
                            const int* __restrict__ flag, int* __restrict__ deg) {
    int e = blockIdx.x * blockDim.x + threadIdx.x;
    if (e >= E + N) return;
    atomicAdd(&deg[edge_dst(ei, E, e, *flag)], 1);
}
__global__ void scatter_kernel(const int* __restrict__ ei, int E, int N,
                               const int* __restrict__ flag, const int* __restrict__ rowptr,
                               int* __restrict__ cnt, int* __restrict__ ecol) {
    int e = blockIdx.x * blockDim.x + threadIdx.x;
    if (e >= E + N) return;
    int src, dst;
    if (e >= E) { src = dst = e - E; }
    else if (*flag) { src = ei[2 * e]; dst = ei[2 * E + 2 * e]; }
    else            { src = ei[e];     dst = ei[E + e]; }
    int pos = rowptr[dst] + atomicAdd(&cnt[dst], 1);
    ecol[pos] = src;
}
__global__ __launch_bounds__(1024) void scan1_kernel(const int* __restrict__ deg,
                                                     int* __restrict__ tmp,
                                                     int* __restrict__ bsum, int n) {
    __shared__ int ws[16];
    int tid = threadIdx.x, lane = tid & 63, wid = tid >> 6;
    int i = blockIdx.x * 1024 + tid;
    int v = (i < n) ? deg[i] : 0;
    int incl = v;
#pragma unroll
    for (int off = 1; off < 64; off <<= 1) {
        int t2 = __shfl_up(incl, off, 64);
        if (lane >= off) incl += t2;
    }
    if (lane == 63) ws[wid] = incl;
    __syncthreads();
    if (tid < 16) {
        int wv_ = ws[tid], winc = wv_;
#pragma unroll
        for (int off = 1; off < 16; off <<= 1) {
            int t2 = __shfl_up(winc, off, 16);
            if (tid >= off) winc += t2;
        }
        ws[tid] = winc - wv_;
    }
    __syncthreads();
    int excl = incl - v + ws[wid];
    if (i < n) tmp[i] = excl;
    if (tid == 1023) bsum[blockIdx.x] = excl + v;
}
__global__ void scan2_kernel(int* __restrict__ bsum, int nb) {
    int lane = threadIdx.x;
    int v = (lane < nb) ? bsum[lane] : 0;
    int incl = v;
    for (int off = 1; off < 64; off <<= 1) {
        int t = __shfl_up(incl, off, 64);
        if (lane >= off) incl += t;
    }
    int total = __shfl(incl, nb - 1, 64);
    if (lane < nb) bsum[lane] = incl - v;
    if (lane == 0) bsum[nb] = total;
}
__global__ void scan3_kernel(const int* __restrict__ tmp, const int* __restrict__ bsum,
                             int* __restrict__ rowptr, int* __restrict__ cnt, int n, int nb) {
    int i = blockIdx.x * blockDim.x + threadIdx.x;
    if (i > n) return;
    rowptr[i] = (i == n) ? bsum[nb] : tmp[i] + bsum[i >> 10];
    if (i < n) cnt[i] = 0;
}

// standalone gemm1 (fallback path)
__global__ __launch_bounds__(256) void gemm1_kernel(
    const void* __restrict__ xraw, const int* __restrict__ flagF,
    const ushort* __restrict__ BT, ushort* __restrict__ C,
    const float* __restrict__ att, float4* __restrict__ asrc4, float4* __restrict__ adst4, int M) {
    gemm1_body(blockIdx.x, xraw, flagF, BT, C, att, asrc4, adst4, M);
}

// ---------------- agg1: 4 nodes/wave (16 lanes/node, 8 ch/lane); h1 -> hL1 + attdot2 ------
__global__ __launch_bounds__(256) void agg1_kernel(
    const ushort* __restrict__ hsrc, const float4* __restrict__ a_src4,
    const float4* __restrict__ a_dst4, const int* __restrict__ rowptr,
    const int* __restrict__ ecol, const float* __restrict__ bias,
    const float* __restrict__ w2t8, uint4* __restrict__ outz,
    float4* __restrict__ asrc2, float4* __restrict__ adst2, int N) {
    constexpr int SH = 7;  // row = 128 ush
    __shared__ __align__(16) ushort elds[4][4][4][20];  // [wave][head][quarter][16+pad]
    int lane = threadIdx.x & 63, wv = threadIdx.x >> 6;
    int q = lane >> 4, c = lane & 15, qbase = q << 4;
    int n = blockIdx.x * 16 + wv * 4 + q;
    bool nv = n < N;
    int start = 0, end = 0;
    if (nv) { start = rowptr[n]; end = rowptr[n + 1]; }
    int deg = end - start;
    float4 ad = nv ? a_dst4[n] : make_float4(0.f, 0.f, 0.f, 0.f);
    int hh = c >> 2;               // lane's channels 8c..8c+7 all in layer-1 head c/4
    uint laneoff = (uint)c * 8;    // ushort offset (8 ch/lane = 16B)
    float acc[8] = {};
    float ss0 = 0.f, ss1 = 0.f, ss2 = 0.f, ss3 = 0.f;

    for (int cs = 0; cs < deg; cs += 16) {
        int len = min(16, deg - cs);
        bool v = c < len;
        int sv = v ? ecol[start + cs + c] : 0;
        float4 as = a_src4[sv];
        float e0 = v ? __expf(fminf(leaky(as.x + ad.x), 60.f)) : 0.f;
        float e1 = v ? __expf(fminf(leaky(as.y + ad.y), 60.f)) : 0.f;
        float e2 = v ? __expf(fminf(leaky(as.z + ad.z), 60.f)) : 0.f;
        float e3 = v ? __expf(fminf(leaky(as.w + ad.w), 60.f)) : 0.f;
        ushort r0 = f2b(e0), r1 = f2b(e1), r2 = f2b(e2), r3 = f2b(e3);
        elds[wv][0][q][c] = r0; elds[wv][1][q][c] = r1;
        elds[wv][2][q][c] = r2; elds[wv][3][q][c] = r3;
        ss0 += b2f(r0); ss1 += b2f(r1); ss2 += b2f(r2); ss3 += b2f(r3);
        for (int e = 0; e < len; e += 4) {
            int s0 = __shfl(sv, qbase + e + 0, 64);
            int s1 = __shfl(sv, qbase + e + 1, 64);
            int s2 = __shfl(sv, qbase + e + 2, 64);
            int s3 = __shfl(sv, qbase + e + 3, 64);
            uint2 w = *(const uint2*)&elds[wv][hh][q][e];  // (a_e,a_e+1),(a_e+2,a_e+3)
            uint4 h0 = *(const uint4*)(hsrc + (((uint)s0) << SH) + laneoff);
            uint4 h1 = *(const uint4*)(hsrc + (((uint)s1) << SH) + laneoff);
            uint4 h2 = *(const uint4*)(hsrc + (((uint)s2) << SH) + laneoff);
            uint4 h3 = *(const uint4*)(hsrc + (((uint)s3) << SH) + laneoff);
            DOT2PAIR(h0.x, h1.x, w.x, acc[0], acc[1]); DOT2PAIR(h0.y, h1.y, w.x, acc[2], acc[3]);
            DOT2PAIR(h0.z, h1.z, w.x, acc[4], acc[5]); DOT2PAIR(h0.w, h1.w, w.x, acc[6], acc[7]);
            DOT2PAIR(h2.x, h3.x, w.y, acc[0], acc[1]); DOT2PAIR(h2.y, h3.y, w.y, acc[2], acc[3]);
            DOT2PAIR(h2.z, h3.z, w.y, acc[4], acc[5]); DOT2PAIR(h2.w, h3.w, w.y, acc[6], acc[7]);
        }
    }
#pragma unroll
    for (int off = 1; off < 16; off <<= 1) {  // within-quarter reduce
        ss0 += __shfl_xor(ss0, off, 64); ss1 += __shfl_xor(ss1, off, 64);
        ss2 += __shfl_xor(ss2, off, 64); ss3 += __shfl_xor(ss3, off, 64);
    }
    if (!nv) return;
    float ih = (hh == 0) ? 1.f / (ss0 + 1e-16f) : (hh == 1) ? 1.f / (ss1 + 1e-16f)
             : (hh == 2) ? 1.f / (ss2 + 1e-16f) : 1.f / (ss3 + 1e-16f);
    float4 bA = ((const float4*)bias)[2 * c], bB = ((const float4*)bias)[2 * c + 1];
    float o[8];
    o[0] = acc[0] * ih + bA.x; o[1] = acc[1] * ih + bA.y;
    o[2] = acc[2] * ih + bA.z; o[3] = acc[3] * ih + bA.w;
    o[4] = acc[4] * ih + bB.x; o[5] = acc[5] * ih + bB.y;
    o[6] = acc[6] * ih + bB.z; o[7] = acc[7] * ih + bB.w;
#pragma unroll
    for (int j = 0; j < 8; ++j) o[j] = o[j] > 0.f ? o[j] : __expf(o[j]) - 1.f;
    uint4 pk;
    pk.x = (uint)f2b(o[0]) | ((uint)f2b(o[1]) << 16);
    pk.y = (uint)f2b(o[2]) | ((uint)f2b(o[3]) << 16);
    pk.z = (uint)f2b(o[4]) | ((uint)f2b(o[5]) << 16);
    pk.w = (uint)f2b(o[6]) | ((uint)f2b(o[7]) << 16);
    outz[(size_t)n * 16 + c] = pk;

    // fused attdot2: a2[oidx] = hL1[n] . w2t8[oidx]
    float po[8];
#pragma unroll
    for (int oo = 0; oo < 8; ++oo) {
        float4 wA = ((const float4*)(w2t8 + oo * 128))[2 * c];
        float4 wB = ((const float4*)(w2t8 + oo * 128))[2 * c + 1];
        po[oo] = o[0] * wA.x + o[1] * wA.y + o[2] * wA.z + o[3] * wA.w
               + o[4] * wB.x + o[5] * wB.y + o[6] * wB.z + o[7] * wB.w;
    }
#pragma unroll
    for (int off = 1; off < 16; off <<= 1)
#pragma unroll
        for (int oo = 0; oo < 8; ++oo) po[oo] += __shfl_xor(po[oo], off, 64);
    if (c == 0) {
        asrc2[n] = make_float4(po[0], po[1], po[2], po[3]);
        adst2[n] = make_float4(po[4], po[5], po[6], po[7]);
    }
}

// ---- agg2: 4 nodes/wave per-head aggregate of hL1, FUSED output GEMM (K=512 vs W2sT) ----
__global__ __launch_bounds__(256) void agg2_kernel(
    const ushort* __restrict__ hsrc, const float4* __restrict__ a_src4,
    const float4* __restrict__ a_dst4, const int* __restrict__ rowptr,
    const int* __restrict__ ecol, const ushort* __restrict__ W2sT,
    const float* __restrict__ b2, float* __restrict__ outp, int N) {
    constexpr int SH = 7;
    __shared__ __align__(16) ushort elds[4][4][4][20];  // [wave][head][quarter][16+pad]
    __shared__ __align__(16) ushort lds_a[16][520];     // 16 z2-rows (K=512), +8 pad
    int lane = threadIdx.x & 63, wv = threadIdx.x >> 6;
    int q = lane >> 4, c = lane & 15, qbase = q << 4;
    int n = blockIdx.x * 16 + wv * 4 + q;
    bool nv = n < N;
    int start = 0, end = 0;
    if (nv) { start = rowptr[n]; end = rowptr[n + 1]; }
    int deg = end - start;
    float4 ad = nv ? a_dst4[n] : make_float4(0.f, 0.f, 0.f, 0.f);
    uint laneoff = (uint)c * 8;  // 8 ch/lane = 16B
    float a0_[8] = {}, a1_[8] = {}, a2_[8] = {}, a3_[8] = {};  // [head][8 ch]
    float ss0 = 0.f, ss1 = 0.f, ss2 = 0.f, ss3 = 0.f;

    for (int cs = 0; cs < deg; cs += 16) {
        int len = min(16, deg - cs);
        bool v = c < len;
        int sv = v ? ecol[start + cs + c] : 0;
        float4 as = a_src4[sv];
        float e0 = v ? __expf(fminf(leaky(as.x + ad.x), 60.f)) : 0.f;
        float e1 = v ? __expf(fminf(leaky(as.y + ad.y), 60.f)) : 0.f;
        float e2 = v ? __expf(fminf(leaky(as.z + ad.z), 60.f)) : 0.f;
        float e3 = v ? __expf(fminf(leaky(as.w + ad.w), 60.f)) : 0.f;
        ushort r0 = f2b(e0), r1 = f2b(e1), r2 = f2b(e2), r3 = f2b(e3);
        elds[wv][0][q][c] = r0; elds[wv][1][q][c] = r1;
        elds[wv][2][q][c] = r2; elds[wv][3][q][c] = r3;
        ss0 += b2f(r0); ss1 += b2f(r1); ss2 += b2f(r2); ss3 += b2f(r3);
        for (int e = 0; e < len; e += 4) {
            int s0 = __shfl(sv, qbase + e + 0, 64);
            int s1 = __shfl(sv, qbase + e + 1, 64);
            int s2 = __shfl(sv, qbase + e + 2, 64);
            int s3 = __shfl(sv, qbase + e + 3, 64);
            uint2 w0 = *(const uint2*)&elds[wv][0][q][e];
            uint2 w1 = *(const uint2*)&elds[wv][1][q][e];
            uint2 w2 = *(const uint2*)&elds[wv][2][q][e];
            uint2 w3 = *(const uint2*)&elds[wv][3][q][e];
            uint4 h0 = *(const uint4*)(hsrc + (((uint)s0) << SH) + laneoff);
            uint4 h1 = *(const uint4*)(hsrc + (((uint)s1) << SH) + laneoff);
            uint4 h2 = *(const uint4*)(hsrc + (((uint)s2) << SH) + laneoff);
            uint4 h3 = *(const uint4*)(hsrc + (((uint)s3) << SH) + laneoff);
            // row perms are shared (CSE) across the 4 head-weight lines
            DOT2PAIR(h0.x, h1.x, w0.x, a0_[0], a0_[1]); DOT2PAIR(h0.y, h1.y, w0.x, a0_[2], a0_[3]);
            DOT2PAIR(h0.z, h1.z, w0.x, a0_[4], a0_[5]); DOT2PAIR(h0.w, h1.w, w0.x, a0_[6], a0_[7]);
            DOT2PAIR(h0.x, h1.x, w1.x, a1_[0], a1_[1]); DOT2PAIR(h0.y, h1.y, w1.x, a1_[2], a1_[3]);
            DOT2PAIR(h0.z, h1.z, w1.x, a1_[4], a1_[5]); DOT2PAIR(h0.w, h1.w, w1.x, a1_[6], a1_[7]);
            DOT2PAIR(h0.x, h1.x, w2.x, a2_[0], a2_[1]); DOT2PAIR(h0.y, h1.y, w2.x, a2_[2], a2_[3]);
            DOT2PAIR(h0.z, h1.z, w2.x, a2_[4], a2_[5]); DOT2PAIR(h0.w, h1.w, w2.x, a2_[6], a2_[7]);
            DOT2PAIR(h0.x, h1.x, w3.x, a3_[0], a3_[1]); DOT2PAIR(h0.y, h1.y, w3.x, a3_[2], a3_[3]);
            DOT2PAIR(h0.z, h1.z, w3.x, a3_[4], a3_[5]); DOT2PAIR(h0.w, h1.w, w3.x, a3_[6], a3_[7]);
            DOT2PAIR(h2.x, h3.x, w0.y, a0_[0], a0_[1]); DOT2PAIR(h2.y, h3.y, w0.y, a0_[2], a0_[3]);
            DOT2PAIR(h2.z, h3.z, w0.y, a0_[4], a0_[5]); DOT2PAIR(h2.w, h3.w, w0.y, a0_[6], a0_[7]);
            DOT2PAIR(h2.x, h3.x, w1.y, a1_[0], a1_[1]); DOT2PAIR(h2.y, h3.y, w1.y, a1_[2], a1_[3]);
            DOT2PAIR(h2.z, h3.z, w1.y, a1_[4], a1_[5]); DOT2PAIR(h2.w, h3.w, w1.y, a1_[6], a1_[7]);
            DOT2PAIR(h2.x, h3.x, w2.y, a2_[0], a2_[1]); DOT2PAIR(h2.y, h3.y, w2.y, a2_[2], a2_[3]);
            DOT2PAIR(h2.z, h3.z, w2.y, a2_[4], a2_[5]); DOT2PAIR(h2.w, h3.w, w2.y, a2_[6], a2_[7]);
            DOT2PAIR(h2.x, h3.x, w3.y, a3_[0], a3_[1]); DOT2PAIR(h2.y, h3.y, w3.y, a3_[2], a3_[3]);
            DOT2PAIR(h2.z, h3.z, w3.y, a3_[4], a3_[5]); DOT2PAIR(h2.w, h3.w, w3.y, a3_[6], a3_[7]);
        }
    }
#pragma unroll
    for (int off = 1; off < 16; off <<= 1) {
        ss0 += __shfl_xor(ss0, off, 64); ss1 += __shfl_xor(ss1, off, 64);
        ss2 += __shfl_xor(ss2, off, 64); ss3 += __shfl_xor(ss3, off, 64);
    }
    // normalize (invalid nodes: acc=0 -> z=0) and stage z2 rows into LDS A-tile
    float i0 = 1.f / (ss0 + 1e-16f), i1 = 1.f / (ss1 + 1e-16f);
    float i2 = 1.f / (ss2 + 1e-16f), i3 = 1.f / (ss3 + 1e-16f);
    int slot = wv * 4 + q;
    uint4 pk;
    pk.x = (uint)f2b(a0_[0] * i0) | ((uint)f2b(a0_[1] * i0) << 16);
    pk.y = (uint)f2b(a0_[2] * i0) | ((uint)f2b(a0_[3] * i0) << 16);
    pk.z = (uint)f2b(a0_[4] * i0) | ((uint)f2b(a0_[5] * i0) << 16);
    pk.w = (uint)f2b(a0_[6] * i0) | ((uint)f2b(a0_[7] * i0) << 16);
    *(uint4*)&lds_a[slot][0 * 128 + 8 * c] = pk;
    pk.x = (uint)f2b(a1_[0] * i1) | ((uint)f2b(a1_[1] * i1) << 16);
    pk.y = (uint)f2b(a1_[2] * i1) | ((uint)f2b(a1_[3] * i1) << 16);
    pk.z = (uint)f2b(a1_[4] * i1) | ((uint)f2b(a1_[5] * i1) << 16);
    pk.w = (uint)f2b(a1_[6] * i1) | ((uint)f2b(a1_[7] * i1) << 16);
    *(uint4*)&lds_a[slot][1 * 128 + 8 * c] = pk;
    pk.x = (uint)f2b(a2_[0] * i2) | ((uint)f2b(a2_[1] * i2) << 16);
    pk.y = (uint)f2b(a2_[2] * i2) | ((uint)f2b(a2_[3] * i2) << 16);
    pk.z = (uint)f2b(a2_[4] * i2) | ((uint)f2b(a2_[5] * i2) << 16);
    pk.w = (uint)f2b(a2_[6] * i2) | ((uint)f2b(a2_[7] * i2) << 16);
    *(uint4*)&lds_a[slot][2 * 128 + 8 * c] = pk;
    pk.x = (uint)f2b(a3_[0] * i3) | ((uint)f2b(a3_[1] * i3) << 16);
    pk.y = (uint)f2b(a3_[2] * i3) | ((uint)f2b(a3_[3] * i3) << 16);
    pk.z = (uint)f2b(a3_[4] * i3) | ((uint)f2b(a3_[5] * i3) << 16);
    pk.w = (uint)f2b(a3_[6] * i3) | ((uint)f2b(a3_[7] * i3) << 16);
    *(uint4*)&lds_a[slot][3 * 128 + 8 * c] = pk;
    __syncthreads();

    // fused gemm2: wave wv computes out cols wv*16..+15 for the block's 16 nodes (K=512 MFMA)
    int m = lane & 15, quad = lane >> 4;
    const bf16x8* arow = (const bf16x8*)&lds_a[m][0];
    const bf16x8* brow = (const bf16x8*)(W2sT + (size_t)(wv * 16 + m) * 512);
    floatx4 acc2 = {};
#pragma unroll
    for (int kk = 0; kk < 16; ++kk)
        acc2 = __builtin_amdgcn_mfma_f32_16x16x32_bf16(arow[4 * kk + quad], brow[4 * kk + quad], acc2, 0, 0, 0);
    float bb = b2[wv * 16 + m];
#pragma unroll
    for (int r = 0; r < 4; ++r) {
        int row = quad * 4 + r;  // C/D: col=lane&15, row=quad*4+r
        int node = blockIdx.x * 16 + row;
        if (node < N) outp[(size_t)node * 64 + wv * 16 + m] = acc2[r] + bb;
    }
}

// ---------------- launch ----------------
extern "C" void kernel_launch(void* const* d_in, const int* in_sizes, int n_in,
                              void* d_out, int out_size, void* d_ws, size_t ws_size,
                              hipStream_t stream) {
    // setup_inputs order: x, edge_index, W1, att_src1, att_dst1, bias1, W2, att_src2, att_dst2, bias2
    const void* x_raw = d_in[0];
    const int*  ei    = (const int*)d_in[1];
    const void* W1_p  = d_in[2];
    const void* as1_p = d_in[3];
    const void* ad1_p = d_in[4];
    const void* b1_p  = d_in[5];
    const void* W2_p  = d_in[6];
    const void* as2_p = d_in[7];
    const void* ad2_p = d_in[8];
    const void* b2_p  = d_in[9];

    const int F_IN = 128;
    const int N = in_sizes[0] / F_IN;   // 50000
    const int E = in_sizes[1] / 2;      // 800000
    const int ET = E + N;
    const int NB = (N + 1023) / 1024;
    const int NBUK = (N + 255) >> 8;    // buckets; packed path needs N<=65536
    const int NBH = (ET + 4095) / 4096; // bhist-role blocks inside prep

    char* p = (char*)d_ws;
    auto alloc = [&](size_t bytes) { char* r = p; p += (bytes + 255) & ~(size_t)255; return r; };
    ushort* W1T   = (ushort*)alloc(128 * 128 * 2);
    ushort* W2sT  = (ushort*)alloc(64 * 512 * 2);
    float*  att1f = (float*)alloc(256 * 4);
    float*  w2t8  = (float*)alloc(8 * 128 * 4);
    float*  b1f   = (float*)alloc(128 * 4);
    float*  b2f   = (float*)alloc(64 * 4);
    ushort* h1    = (ushort*)alloc((size_t)N * 128 * 2);
    ushort* hL1   = (ushort*)alloc((size_t)N * 128 * 2);
    float*  asrc1 = (float*)alloc((size_t)N * 4 * 4);
    float*  adst1 = (float*)alloc((size_t)N * 4 * 4);
    float*  asrc2 = (float*)alloc((size_t)N * 4 * 4);
    float*  adst2 = (float*)alloc((size_t)N * 4 * 4);
    int* deg    = (int*)alloc((size_t)N * 4);   // fallback only
    int* cnt    = (int*)alloc((size_t)N * 4);   // fallback only
    int* tmp    = (int*)alloc((size_t)N * 4);   // fallback only
    int* bsum   = (int*)alloc(128 * 4);         // fallback only
    int* rowptr = (int*)alloc((size_t)(N + 1) * 4);
    int* ecol   = (int*)alloc((size_t)ET * 4);
    uint* ebuf  = (uint*)alloc((size_t)ET * 4);
    int* bcnt   = (int*)alloc(256 * 4);
    int* gofs   = (int*)alloc(256 * 4);   // contiguous with bcnt (both 1024B, 256B-aligned)
    int* flagI  = (int*)alloc(256);
    int* flagF  = (int*)alloc(256);

    hipMemsetAsync(bcnt, 0, 2 * 256 * 4, stream);  // bcnt + gofs
    // merged prep: W1T + smalls/flags + w2t8 + W2sT + bhist (x-conv lives in gemm1 body)
    prep_kernel<<<64 + 1 + 4 + 128 + NBH, 256, 0, stream>>>(
        x_raw, W1_p, as1_p, ad1_p, b1_p, b2_p, W2_p, as2_p, ad2_p, ei, E, ET,
        W1T, att1f, b1f, b2f, w2t8, W2sT, flagI, flagF, bcnt);

    int gblocks = (N + 63) / 64;
    if (N <= 65536) {  // bucketed CSR; part fused with gemm1 (independent workloads)
        int npart = (ET + 8191) / 8192;
        partg_kernel<<<npart + gblocks, 256, 0, stream>>>(
            ei, E, ET, flagI, bcnt, gofs, ebuf, NBUK, npart,
            x_raw, flagF, W1T, h1, att1f, (float4*)asrc1, (float4*)adst1, N);
        bfinal_kernel<<<NBUK, 256, 0, stream>>>(ebuf, bcnt, rowptr, ecol, N, NBUK);
    } else {  // fallback: random-scatter path
        hipMemsetAsync(deg, 0, (size_t)N * 4, stream);
        int eblocks = (ET + 255) / 256;
        hist_kernel<<<eblocks, 256, 0, stream>>>(ei, E, N, flagI, deg);
        scan1_kernel<<<NB, 1024, 0, stream>>>(deg, tmp, bsum, N);
        scan2_kernel<<<1, 64, 0, stream>>>(bsum, NB);
        scan3_kernel<<<(N + 256) / 256, 256, 0, stream>>>(tmp, bsum, rowptr, cnt, N, NB);
        scatter_kernel<<<eblocks, 256, 0, stream>>>(ei, E, N, flagI, rowptr, cnt, ecol);
        gemm1_kernel<<<gblocks, 256, 0, stream>>>(
            x_raw, flagF, W1T, h1, att1f, (float4*)asrc1, (float4*)adst1, N);
    }

    int nblocks16 = (N + 15) / 16;
    // ---- layer 1 aggregation ----
    agg1_kernel<<<nblocks16, 256, 0, stream>>>(
        h1, (const float4*)asrc1, (const float4*)adst1, rowptr, ecol, b1f, w2t8,
        (uint4*)hL1, (float4*)asrc2, (float4*)adst2, N);
    // ---- layer 2 (agg + output GEMM fused) ----
    agg2_kernel<<<nblocks16, 256, 0, stream>>>(
        hL1, (const float4*)asrc2, (const float4*)adst2, rowptr, ecol, W2sT, b2f,
        (float*)d_out, N);
}